// Round 1
// baseline (13350.659 us; speedup 1.0000x reference)
//
#include <hip/hip_runtime.h>
#include <cstdint>
#include <cstddef>

#define NN 20000
#define NE 320000
#define HD 512
#define NG 400
#define FIN 3020
#define NHID ((size_t)NN * HD)

typedef __attribute__((ext_vector_type(4))) float f32x4;
typedef __attribute__((ext_vector_type(8))) short s16x8;
typedef __attribute__((ext_vector_type(4))) short s16x4;

__device__ __forceinline__ unsigned short f2bf(float f) {
  uint32_t u = __builtin_bit_cast(uint32_t, f);
  uint32_t r = u + 0x7fffu + ((u >> 16) & 1u);
  return (unsigned short)(r >> 16);
}
__device__ __forceinline__ float bf2f(unsigned short h) {
  return __builtin_bit_cast(float, (uint32_t)h << 16);
}

// ---------------- cast x (f32 -> bf16), 4 elems/thread ----------------
__global__ void cast_x_kernel(const float* __restrict__ in, unsigned short* __restrict__ outp) {
  size_t i = ((size_t)blockIdx.x * 256 + threadIdx.x) * 4;
  f32x4 v = *(const f32x4*)(in + i);
  s16x4 o;
  #pragma unroll
  for (int j = 0; j < 4; ++j) o[j] = (short)f2bf(v[j]);
  *(s16x4*)(outp + i) = o;
}

// ---------------- transpose+cast weights: wt[l][j][k] = bf16(w[l][k][j]) ----------------
__global__ void transpose_w_kernel(const float* __restrict__ w, unsigned short* __restrict__ wt) {
  int o = blockIdx.x * 256 + threadIdx.x;      // 3*512*512 total
  int k = o & 511, j = (o >> 9) & 511, l = o >> 18;
  wt[o] = f2bf(w[((size_t)l << 18) + ((size_t)k << 9) + j]);
}

// ---------------- scatter-add: agg[dst] += h[src], one wave per edge ----------------
__global__ void scatter_kernel(const unsigned short* __restrict__ hb,
                               const int* __restrict__ ei,
                               float* __restrict__ agg) {
  size_t t = (size_t)blockIdx.x * 256 + threadIdx.x;
  int e = (int)(t >> 6);
  int lane = (int)(t & 63);
  if (e >= NE) return;
  int src = ei[e];
  int dst = ei[NE + e];
  s16x8 v = *(const s16x8*)(hb + (size_t)src * HD + (lane << 3));
  float* d = agg + (size_t)dst * HD + (lane << 3);
  #pragma unroll
  for (int i = 0; i < 8; ++i) unsafeAtomicAdd(d + i, bf2f((unsigned short)v[i]));
}

// ---------------- hsb = bf16(hb + agg); agg = 0 ----------------
__global__ void addcvt_kernel(const unsigned short* __restrict__ hb,
                              float* __restrict__ agg,
                              unsigned short* __restrict__ hs) {
  size_t i = ((size_t)blockIdx.x * 256 + threadIdx.x) * 4;
  s16x4 h = *(const s16x4*)(hb + i);
  f32x4 a = *(const f32x4*)(agg + i);
  s16x4 o;
  #pragma unroll
  for (int j = 0; j < 4; ++j) o[j] = (short)f2bf(bf2f((unsigned short)h[j]) + a[j]);
  *(s16x4*)(hs + i) = o;
  f32x4 z = {0.f, 0.f, 0.f, 0.f};
  *(f32x4*)(agg + i) = z;
}

// ---------------- GEMM (M x 512) @ (512 x 512) with fused epilogue ----------------
// A: bf16 row-major M x 512.  Bt: bf16 [j][k] (transposed weights) 512 x 512.
// EPI 1: +bias, prelu(slope), BN affine -> bf16 out
// EPI 2: +bias, prelu(slope), relu -> bf16 out
// EPI 3: +bias, prelu(slope), relu -> f32 out
template <int EPI>
__global__ __launch_bounds__(256, 2) void gemm_bf16(
    const unsigned short* __restrict__ A, const unsigned short* __restrict__ Bt,
    const float* __restrict__ bias, const float* __restrict__ slope,
    const float* __restrict__ bnm, const float* __restrict__ bnv,
    const float* __restrict__ bng, const float* __restrict__ bnb,
    void* __restrict__ Cout, int M) {
  __shared__ unsigned short lds[16384];  // A tile 128x64 (16KB) + B tile 128x64 (16KB)
  char* ldsb = (char*)lds;
  const int tid = threadIdx.x;
  const int lane = tid & 63;
  const int wid = tid >> 6;
  const int wm = wid >> 1, wn = wid & 1;
  const int m0 = blockIdx.x * 128;
  const int n0 = blockIdx.y * 128;

  f32x4 acc[4][4];
  #pragma unroll
  for (int m = 0; m < 4; ++m)
    #pragma unroll
    for (int n = 0; n < 4; ++n) acc[m][n] = (f32x4){0.f, 0.f, 0.f, 0.f};

  const int row_s = tid >> 3;   // 0..31
  const int slot_s = tid & 7;   // 0..7
  const unsigned ldso_w = (unsigned)(wid << 10);

  for (int kk = 0; kk < HD; kk += 64) {
    __syncthreads();
    #pragma unroll
    for (int i = 0; i < 4; ++i) {
      int ra = i * 32 + row_s;
      int rga = m0 + ra; rga = rga < M ? rga : M - 1;
      const unsigned short* ga = A + (size_t)rga * HD + (kk + ((slot_s ^ (ra & 7)) << 3));
      __builtin_amdgcn_global_load_lds(
          (const __attribute__((address_space(1))) unsigned int*)(const void*)ga,
          (__attribute__((address_space(3))) unsigned int*)(void*)(ldsb + (unsigned)(i * 4096) + ldso_w),
          16, 0, 0);
    }
    #pragma unroll
    for (int i = 0; i < 4; ++i) {
      int rb = i * 32 + row_s;
      const unsigned short* gb = Bt + (size_t)(n0 + rb) * HD + (kk + ((slot_s ^ (rb & 7)) << 3));
      __builtin_amdgcn_global_load_lds(
          (const __attribute__((address_space(1))) unsigned int*)(const void*)gb,
          (__attribute__((address_space(3))) unsigned int*)(void*)(ldsb + 16384u + (unsigned)(i * 4096) + ldso_w),
          16, 0, 0);
    }
    __syncthreads();

    const unsigned swz = (unsigned)((lane & 7) << 4);
    const unsigned koff = (unsigned)((lane >> 4) << 4);
    const unsigned arow = (unsigned)((wm * 64 + (lane & 15)) * 128);
    const unsigned brow = 16384u + (unsigned)((wn * 64 + (lane & 15)) * 128);
    #pragma unroll
    for (int s = 0; s < 2; ++s) {
      s16x8 af[4], bfr[4];
      #pragma unroll
      for (int m = 0; m < 4; ++m)
        af[m] = *(const s16x8*)(ldsb + ((arow + (unsigned)(m * 2048 + s * 64) + koff) ^ swz));
      #pragma unroll
      for (int n = 0; n < 4; ++n)
        bfr[n] = *(const s16x8*)(ldsb + ((brow + (unsigned)(n * 2048 + s * 64) + koff) ^ swz));
      #pragma unroll
      for (int m = 0; m < 4; ++m)
        #pragma unroll
        for (int n = 0; n < 4; ++n)
          acc[m][n] = __builtin_amdgcn_mfma_f32_16x16x32_bf16(af[m], bfr[n], acc[m][n], 0, 0, 0);
    }
  }

  const float al = slope[0];
  const int colb = n0 + wn * 64 + (lane & 15);
  const int rowb = m0 + wm * 64 + ((lane >> 4) << 2);
  #pragma unroll
  for (int n = 0; n < 4; ++n) {
    const int j = colb + n * 16;
    const float bi = bias[j];
    float sc = 1.f, sh = 0.f;
    if (EPI == 1) {
      sc = bng[j] * (1.f / sqrtf(bnv[j] + 1e-5f));
      sh = bnb[j] - bnm[j] * sc;
    }
    #pragma unroll
    for (int m = 0; m < 4; ++m) {
      #pragma unroll
      for (int r = 0; r < 4; ++r) {
        int row = rowb + m * 16 + r;
        if (row < M) {
          float v = acc[m][n][r] + bi;
          v = v >= 0.f ? v : al * v;
          if (EPI == 1) v = v * sc + sh;
          else v = fmaxf(v, 0.f);
          if (EPI == 3) ((float*)Cout)[(size_t)row * HD + j] = v;
          else ((unsigned short*)Cout)[(size_t)row * HD + j] = f2bf(v);
        }
      }
    }
  }
}

// ---------------- pooling: batch is sorted -> contiguous segments ----------------
__device__ __forceinline__ int lbound(const int* __restrict__ a, int n, int v) {
  int lo = 0, hi = n;
  while (lo < hi) { int m = (lo + hi) >> 1; if (a[m] < v) lo = m + 1; else hi = m; }
  return lo;
}

__global__ void pool_kernel(const float* __restrict__ hf, const int* __restrict__ batch,
                            float* __restrict__ pooled) {
  int g = blockIdx.x, j = threadIdx.x;  // 512 threads
  int lo = lbound(batch, NN, g);
  int hi = lbound(batch, NN, g + 1);
  float s = 0.f;
  for (int n = lo; n < hi; ++n) s += hf[(size_t)n * HD + j];
  pooled[(size_t)g * HD + j] = s;
}

// ---------------- final FC head: x_l + sigmoid out ----------------
__global__ __launch_bounds__(256) void fc_kernel(
    const float* __restrict__ pooled, const float* __restrict__ stats,
    const float* __restrict__ adj, const float* __restrict__ w1,
    const float* __restrict__ b1, const float* __restrict__ w2,
    const float* __restrict__ b2, float* __restrict__ outp) {
  __shared__ float xc[FIN];
  __shared__ float red[256];
  int g = blockIdx.x, t = threadIdx.x;
  for (int i = t; i < HD; i += 256) xc[i] = pooled[(size_t)g * HD + i];
  if (t < 8) xc[HD + t] = stats[g * 8 + t];
  for (int i = t; i < 2500; i += 256) xc[520 + i] = adj[(size_t)g * 2500 + i];
  __syncthreads();
  float a0 = 0.f, a1 = 0.f, a2 = 0.f, a3 = 0.f;
  for (int k = 0; k < FIN; k += 4) {
    a0 = fmaf(xc[k + 0], w1[(size_t)(k + 0) * 256 + t], a0);
    a1 = fmaf(xc[k + 1], w1[(size_t)(k + 1) * 256 + t], a1);
    a2 = fmaf(xc[k + 2], w1[(size_t)(k + 2) * 256 + t], a2);
    a3 = fmaf(xc[k + 3], w1[(size_t)(k + 3) * 256 + t], a3);
  }
  float xl = fmaxf(b1[t] + ((a0 + a1) + (a2 + a3)), 0.f);
  outp[NG + g * 256 + t] = xl;
  red[t] = xl * w2[t];
  __syncthreads();
  for (int s = 128; s > 0; s >>= 1) {
    if (t < s) red[t] += red[t + s];
    __syncthreads();
  }
  if (t == 0) outp[g] = 1.f / (1.f + expf(-(red[0] + b2[0])));
}

extern "C" void kernel_launch(void* const* d_in, const int* in_sizes, int n_in,
                              void* d_out, int out_size, void* d_ws, size_t ws_size,
                              hipStream_t stream) {
  const float* x = (const float*)d_in[0];
  const int* ei = (const int*)d_in[1];
  const int* batch = (const int*)d_in[2];
  const float* stats = (const float*)d_in[3];
  const float* adj = (const float*)d_in[4];
  const float* w1 = (const float*)d_in[5];
  const float* b1 = (const float*)d_in[6];
  const float* a1 = (const float*)d_in[7];
  const float* bng = (const float*)d_in[8];
  const float* bnb = (const float*)d_in[9];
  const float* bnm = (const float*)d_in[10];
  const float* bnv = (const float*)d_in[11];
  const float* w2 = (const float*)d_in[12];
  const float* b2 = (const float*)d_in[13];
  const float* a2 = (const float*)d_in[14];
  const float* fc1w = (const float*)d_in[15];
  const float* fc1b = (const float*)d_in[16];
  const float* fc2w = (const float*)d_in[17];
  const float* fc2b = (const float*)d_in[18];
  float* outp = (float*)d_out;

  char* ws = (char*)d_ws;
  unsigned short* hb = (unsigned short*)ws;   ws += NHID * 2;
  unsigned short* hsb = (unsigned short*)ws;  ws += NHID * 2;
  unsigned short* h1b = (unsigned short*)ws;  ws += NHID * 2;
  float* aggf = (float*)ws;                   ws += NHID * 4;
  unsigned short* w1t = (unsigned short*)ws;  ws += (size_t)3 * 512 * 512 * 2;
  unsigned short* w2t = (unsigned short*)ws;  ws += (size_t)3 * 512 * 512 * 2;
  float* pooled = (float*)ws;                 ws += (size_t)NG * HD * 4;

  cast_x_kernel<<<(int)(NHID / 1024), 256, 0, stream>>>(x, hb);
  transpose_w_kernel<<<3072, 256, 0, stream>>>(w1, w1t);
  transpose_w_kernel<<<3072, 256, 0, stream>>>(w2, w2t);
  hipMemsetAsync(aggf, 0, NHID * 4, stream);

  dim3 ggrid(157, 4, 1);
  for (int l = 0; l < 3; ++l) {
    scatter_kernel<<<NE / 4, 256, 0, stream>>>(hb, ei, aggf);
    addcvt_kernel<<<(int)(NHID / 1024), 256, 0, stream>>>(hb, aggf, hsb);
    gemm_bf16<1><<<ggrid, 256, 0, stream>>>(hsb, w1t + (size_t)l * 262144,
        b1 + l * 512, a1 + l, bnm + l * 512, bnv + l * 512, bng + l * 512, bnb + l * 512,
        (void*)h1b, NN);
    if (l < 2) {
      gemm_bf16<2><<<ggrid, 256, 0, stream>>>(h1b, w2t + (size_t)l * 262144,
          b2 + l * 512, a2 + l, nullptr, nullptr, nullptr, nullptr, (void*)hb, NN);
    } else {
      gemm_bf16<3><<<ggrid, 256, 0, stream>>>(h1b, w2t + (size_t)l * 262144,
          b2 + l * 512, a2 + l, nullptr, nullptr, nullptr, nullptr, (void*)aggf, NN);
    }
  }

  pool_kernel<<<NG, 512, 0, stream>>>(aggf, batch, pooled);
  fc_kernel<<<NG, 256, 0, stream>>>(pooled, stats, adj, fc1w, fc1b, fc2w, fc2b, outp);
}

// Round 2
// 477.215 us; speedup vs baseline: 27.9762x; 27.9762x over previous
//
#include <hip/hip_runtime.h>
#include <cstdint>
#include <cstddef>

#define NN 20000
#define NE 320000
#define HD 512
#define NG 400
#define FIN 3020
#define NHID ((size_t)NN * HD)

typedef __attribute__((ext_vector_type(4))) float f32x4;
typedef __attribute__((ext_vector_type(8))) short s16x8;
typedef __attribute__((ext_vector_type(4))) short s16x4;

__device__ __forceinline__ unsigned short f2bf(float f) {
  uint32_t u = __builtin_bit_cast(uint32_t, f);
  uint32_t r = u + 0x7fffu + ((u >> 16) & 1u);
  return (unsigned short)(r >> 16);
}
__device__ __forceinline__ float bf2f(unsigned short h) {
  return __builtin_bit_cast(float, (uint32_t)h << 16);
}

// ---------------- cast x (f32 -> bf16), 4 elems/thread ----------------
__global__ void cast_x_kernel(const float* __restrict__ in, unsigned short* __restrict__ outp) {
  size_t i = ((size_t)blockIdx.x * 256 + threadIdx.x) * 4;
  f32x4 v = *(const f32x4*)(in + i);
  s16x4 o;
  #pragma unroll
  for (int j = 0; j < 4; ++j) o[j] = (short)f2bf(v[j]);
  *(s16x4*)(outp + i) = o;
}

// ---------------- transpose+cast weights: wt[l][j][k] = bf16(w[l][k][j]) ----------------
__global__ void transpose_w_kernel(const float* __restrict__ w, unsigned short* __restrict__ wt) {
  int o = blockIdx.x * 256 + threadIdx.x;      // 3*512*512 total
  int k = o & 511, j = (o >> 9) & 511, l = o >> 18;
  wt[o] = f2bf(w[((size_t)l << 18) + ((size_t)k << 9) + j]);
}

// ---------------- CSR build: histogram, scan, fill ----------------
__global__ void hist_kernel(const int* __restrict__ ei, int* __restrict__ deg) {
  int e = blockIdx.x * 256 + threadIdx.x;
  if (e >= NE) return;
  atomicAdd(&deg[ei[NE + e]], 1);
}

__global__ __launch_bounds__(1024) void scan_kernel(const int* __restrict__ deg,
                                                    int* __restrict__ rowptr,
                                                    int* __restrict__ cursor) {
  __shared__ int s[1024];
  int t = threadIdx.x;
  int base = t * 20;
  int local[20];
  int sum = 0;
  #pragma unroll
  for (int i = 0; i < 20; ++i) {
    int idx = base + i;
    int d = idx < NN ? deg[idx] : 0;
    local[i] = sum;
    sum += d;
  }
  s[t] = sum;
  __syncthreads();
  for (int off = 1; off < 1024; off <<= 1) {
    int v = (t >= off) ? s[t - off] : 0;
    __syncthreads();
    s[t] += v;
    __syncthreads();
  }
  int pre = (t > 0) ? s[t - 1] : 0;
  #pragma unroll
  for (int i = 0; i < 20; ++i) {
    int idx = base + i;
    if (idx < NN) {
      rowptr[idx] = pre + local[i];
      cursor[idx] = pre + local[i];
    }
  }
  if (t == 1023) rowptr[NN] = s[1023];
}

__global__ void fill_kernel(const int* __restrict__ ei, int* __restrict__ cursor,
                            int* __restrict__ col) {
  int e = blockIdx.x * 256 + threadIdx.x;
  if (e >= NE) return;
  int src = ei[e];
  int dst = ei[NE + e];
  int p = atomicAdd(&cursor[dst], 1);
  col[p] = src;
}

// ---------------- gather-sum: hs[n] = bf16(h[n] + sum_{e: dst=n} h[src]) ----------------
__global__ __launch_bounds__(256) void gather_kernel(
    const unsigned short* __restrict__ hb, const int* __restrict__ rowptr,
    const int* __restrict__ col, unsigned short* __restrict__ hs) {
  int n = blockIdx.x * 4 + (threadIdx.x >> 6);
  int lane = threadIdx.x & 63;
  if (n >= NN) return;
  int lo = rowptr[n], hi = rowptr[n + 1];
  size_t off = (size_t)(lane << 3);
  s16x8 hv = *(const s16x8*)(hb + (size_t)n * HD + off);
  float acc0[8], acc1[8];
  #pragma unroll
  for (int i = 0; i < 8; ++i) {
    acc0[i] = bf2f((unsigned short)hv[i]);
    acc1[i] = 0.f;
  }
  int j = lo;
  for (; j + 2 <= hi; j += 2) {
    int c0 = col[j], c1 = col[j + 1];
    s16x8 v0 = *(const s16x8*)(hb + (size_t)c0 * HD + off);
    s16x8 v1 = *(const s16x8*)(hb + (size_t)c1 * HD + off);
    #pragma unroll
    for (int i = 0; i < 8; ++i) {
      acc0[i] += bf2f((unsigned short)v0[i]);
      acc1[i] += bf2f((unsigned short)v1[i]);
    }
  }
  if (j < hi) {
    s16x8 v0 = *(const s16x8*)(hb + (size_t)col[j] * HD + off);
    #pragma unroll
    for (int i = 0; i < 8; ++i) acc0[i] += bf2f((unsigned short)v0[i]);
  }
  s16x8 o;
  #pragma unroll
  for (int i = 0; i < 8; ++i) o[i] = (short)f2bf(acc0[i] + acc1[i]);
  *(s16x8*)(hs + (size_t)n * HD + off) = o;
}

// ---------------- GEMM (M x 512) @ (512 x 512) with fused epilogue ----------------
// A: bf16 row-major M x 512.  Bt: bf16 [j][k] (transposed weights) 512 x 512.
// EPI 1: +bias, prelu(slope), BN affine -> bf16 out
// EPI 2: +bias, prelu(slope), relu -> bf16 out
// EPI 3: +bias, prelu(slope), relu -> f32 out
template <int EPI>
__global__ __launch_bounds__(256, 2) void gemm_bf16(
    const unsigned short* __restrict__ A, const unsigned short* __restrict__ Bt,
    const float* __restrict__ bias, const float* __restrict__ slope,
    const float* __restrict__ bnm, const float* __restrict__ bnv,
    const float* __restrict__ bng, const float* __restrict__ bnb,
    void* __restrict__ Cout, int M) {
  __shared__ unsigned short lds[16384];  // A tile 128x64 (16KB) + B tile 128x64 (16KB)
  char* ldsb = (char*)lds;
  const int tid = threadIdx.x;
  const int lane = tid & 63;
  const int wid = tid >> 6;
  const int wm = wid >> 1, wn = wid & 1;
  const int m0 = blockIdx.x * 128;
  const int n0 = blockIdx.y * 128;

  f32x4 acc[4][4];
  #pragma unroll
  for (int m = 0; m < 4; ++m)
    #pragma unroll
    for (int n = 0; n < 4; ++n) acc[m][n] = (f32x4){0.f, 0.f, 0.f, 0.f};

  const int row_s = tid >> 3;   // 0..31
  const int slot_s = tid & 7;   // 0..7
  const unsigned ldso_w = (unsigned)(wid << 10);

  for (int kk = 0; kk < HD; kk += 64) {
    __syncthreads();
    #pragma unroll
    for (int i = 0; i < 4; ++i) {
      int ra = i * 32 + row_s;
      int rga = m0 + ra; rga = rga < M ? rga : M - 1;
      const unsigned short* ga = A + (size_t)rga * HD + (kk + ((slot_s ^ (ra & 7)) << 3));
      __builtin_amdgcn_global_load_lds(
          (const __attribute__((address_space(1))) unsigned int*)(const void*)ga,
          (__attribute__((address_space(3))) unsigned int*)(void*)(ldsb + (unsigned)(i * 4096) + ldso_w),
          16, 0, 0);
    }
    #pragma unroll
    for (int i = 0; i < 4; ++i) {
      int rb = i * 32 + row_s;
      const unsigned short* gb = Bt + (size_t)(n0 + rb) * HD + (kk + ((slot_s ^ (rb & 7)) << 3));
      __builtin_amdgcn_global_load_lds(
          (const __attribute__((address_space(1))) unsigned int*)(const void*)gb,
          (__attribute__((address_space(3))) unsigned int*)(void*)(ldsb + 16384u + (unsigned)(i * 4096) + ldso_w),
          16, 0, 0);
    }
    __syncthreads();

    const unsigned swz = (unsigned)((lane & 7) << 4);
    const unsigned koff = (unsigned)((lane >> 4) << 4);
    const unsigned arow = (unsigned)((wm * 64 + (lane & 15)) * 128);
    const unsigned brow = 16384u + (unsigned)((wn * 64 + (lane & 15)) * 128);
    #pragma unroll
    for (int s = 0; s < 2; ++s) {
      s16x8 af[4], bfr[4];
      #pragma unroll
      for (int m = 0; m < 4; ++m)
        af[m] = *(const s16x8*)(ldsb + ((arow + (unsigned)(m * 2048 + s * 64) + koff) ^ swz));
      #pragma unroll
      for (int n = 0; n < 4; ++n)
        bfr[n] = *(const s16x8*)(ldsb + ((brow + (unsigned)(n * 2048 + s * 64) + koff) ^ swz));
      #pragma unroll
      for (int m = 0; m < 4; ++m)
        #pragma unroll
        for (int n = 0; n < 4; ++n)
          acc[m][n] = __builtin_amdgcn_mfma_f32_16x16x32_bf16(af[m], bfr[n], acc[m][n], 0, 0, 0);
    }
  }

  const float al = slope[0];
  const int colb = n0 + wn * 64 + (lane & 15);
  const int rowb = m0 + wm * 64 + ((lane >> 4) << 2);
  #pragma unroll
  for (int n = 0; n < 4; ++n) {
    const int j = colb + n * 16;
    const float bi = bias[j];
    float sc = 1.f, sh = 0.f;
    if (EPI == 1) {
      sc = bng[j] * (1.f / sqrtf(bnv[j] + 1e-5f));
      sh = bnb[j] - bnm[j] * sc;
    }
    #pragma unroll
    for (int m = 0; m < 4; ++m) {
      #pragma unroll
      for (int r = 0; r < 4; ++r) {
        int row = rowb + m * 16 + r;
        if (row < M) {
          float v = acc[m][n][r] + bi;
          v = v >= 0.f ? v : al * v;
          if (EPI == 1) v = v * sc + sh;
          else v = fmaxf(v, 0.f);
          if (EPI == 3) ((float*)Cout)[(size_t)row * HD + j] = v;
          else ((unsigned short*)Cout)[(size_t)row * HD + j] = f2bf(v);
        }
      }
    }
  }
}

// ---------------- pooling: batch is sorted -> contiguous segments ----------------
__device__ __forceinline__ int lbound(const int* __restrict__ a, int n, int v) {
  int lo = 0, hi = n;
  while (lo < hi) { int m = (lo + hi) >> 1; if (a[m] < v) lo = m + 1; else hi = m; }
  return lo;
}

__global__ void pool_kernel(const float* __restrict__ hf, const int* __restrict__ batch,
                            float* __restrict__ pooled) {
  int g = blockIdx.x, j = threadIdx.x;  // 512 threads
  int lo = lbound(batch, NN, g);
  int hi = lbound(batch, NN, g + 1);
  float s = 0.f;
  for (int n = lo; n < hi; ++n) s += hf[(size_t)n * HD + j];
  pooled[(size_t)g * HD + j] = s;
}

// ---------------- final FC head: x_l + sigmoid out ----------------
__global__ __launch_bounds__(256) void fc_kernel(
    const float* __restrict__ pooled, const float* __restrict__ stats,
    const float* __restrict__ adj, const float* __restrict__ w1,
    const float* __restrict__ b1, const float* __restrict__ w2,
    const float* __restrict__ b2, float* __restrict__ outp) {
  __shared__ float xc[FIN];
  __shared__ float red[256];
  int g = blockIdx.x, t = threadIdx.x;
  for (int i = t; i < HD; i += 256) xc[i] = pooled[(size_t)g * HD + i];
  if (t < 8) xc[HD + t] = stats[g * 8 + t];
  for (int i = t; i < 2500; i += 256) xc[520 + i] = adj[(size_t)g * 2500 + i];
  __syncthreads();
  float a0 = 0.f, a1 = 0.f, a2 = 0.f, a3 = 0.f;
  for (int k = 0; k < FIN; k += 4) {
    a0 = fmaf(xc[k + 0], w1[(size_t)(k + 0) * 256 + t], a0);
    a1 = fmaf(xc[k + 1], w1[(size_t)(k + 1) * 256 + t], a1);
    a2 = fmaf(xc[k + 2], w1[(size_t)(k + 2) * 256 + t], a2);
    a3 = fmaf(xc[k + 3], w1[(size_t)(k + 3) * 256 + t], a3);
  }
  float xl = fmaxf(b1[t] + ((a0 + a1) + (a2 + a3)), 0.f);
  outp[NG + g * 256 + t] = xl;
  red[t] = xl * w2[t];
  __syncthreads();
  for (int s = 128; s > 0; s >>= 1) {
    if (t < s) red[t] += red[t + s];
    __syncthreads();
  }
  if (t == 0) outp[g] = 1.f / (1.f + expf(-(red[0] + b2[0])));
}

extern "C" void kernel_launch(void* const* d_in, const int* in_sizes, int n_in,
                              void* d_out, int out_size, void* d_ws, size_t ws_size,
                              hipStream_t stream) {
  const float* x = (const float*)d_in[0];
  const int* ei = (const int*)d_in[1];
  const int* batch = (const int*)d_in[2];
  const float* stats = (const float*)d_in[3];
  const float* adj = (const float*)d_in[4];
  const float* w1 = (const float*)d_in[5];
  const float* b1 = (const float*)d_in[6];
  const float* a1 = (const float*)d_in[7];
  const float* bng = (const float*)d_in[8];
  const float* bnb = (const float*)d_in[9];
  const float* bnm = (const float*)d_in[10];
  const float* bnv = (const float*)d_in[11];
  const float* w2 = (const float*)d_in[12];
  const float* b2 = (const float*)d_in[13];
  const float* a2 = (const float*)d_in[14];
  const float* fc1w = (const float*)d_in[15];
  const float* fc1b = (const float*)d_in[16];
  const float* fc2w = (const float*)d_in[17];
  const float* fc2b = (const float*)d_in[18];
  float* outp = (float*)d_out;

  char* ws = (char*)d_ws;
  unsigned short* hb = (unsigned short*)ws;   ws += NHID * 2;        // bf16 h
  unsigned short* hsb = (unsigned short*)ws;  ws += NHID * 2;        // bf16 h+agg
  unsigned short* h1b = (unsigned short*)ws;  ws += NHID * 2;        // bf16 mid
  float* hf = (float*)ws;                     ws += NHID * 4;        // f32 final h
  unsigned short* w1t = (unsigned short*)ws;  ws += (size_t)3 * 512 * 512 * 2;
  unsigned short* w2t = (unsigned short*)ws;  ws += (size_t)3 * 512 * 512 * 2;
  float* pooled = (float*)ws;                 ws += (size_t)NG * HD * 4;
  int* deg = (int*)ws;                        ws += (size_t)NN * 4;
  int* rowptr = (int*)ws;                     ws += (size_t)(NN + 4) * 4;
  int* cursor = (int*)ws;                     ws += (size_t)NN * 4;
  int* col = (int*)ws;                        ws += (size_t)NE * 4;

  // CSR build
  hipMemsetAsync(deg, 0, (size_t)NN * 4, stream);
  hist_kernel<<<(NE + 255) / 256, 256, 0, stream>>>(ei, deg);
  scan_kernel<<<1, 1024, 0, stream>>>(deg, rowptr, cursor);
  fill_kernel<<<(NE + 255) / 256, 256, 0, stream>>>(ei, cursor, col);

  cast_x_kernel<<<(int)(NHID / 1024), 256, 0, stream>>>(x, hb);
  transpose_w_kernel<<<3072, 256, 0, stream>>>(w1, w1t);
  transpose_w_kernel<<<3072, 256, 0, stream>>>(w2, w2t);

  dim3 ggrid(157, 4, 1);
  for (int l = 0; l < 3; ++l) {
    gather_kernel<<<NN / 4, 256, 0, stream>>>(hb, rowptr, col, hsb);
    gemm_bf16<1><<<ggrid, 256, 0, stream>>>(hsb, w1t + (size_t)l * 262144,
        b1 + l * 512, a1 + l, bnm + l * 512, bnv + l * 512, bng + l * 512, bnb + l * 512,
        (void*)h1b, NN);
    if (l < 2) {
      gemm_bf16<2><<<ggrid, 256, 0, stream>>>(h1b, w2t + (size_t)l * 262144,
          b2 + l * 512, a2 + l, nullptr, nullptr, nullptr, nullptr, (void*)hb, NN);
    } else {
      gemm_bf16<3><<<ggrid, 256, 0, stream>>>(h1b, w2t + (size_t)l * 262144,
          b2 + l * 512, a2 + l, nullptr, nullptr, nullptr, nullptr, (void*)hf, NN);
    }
  }

  pool_kernel<<<NG, 512, 0, stream>>>(hf, batch, pooled);
  fc_kernel<<<NG, 256, 0, stream>>>(pooled, stats, adj, fc1w, fc1b, fc2w, fc2b, outp);
}

// Round 3
// 442.840 us; speedup vs baseline: 30.1478x; 1.0776x over previous
//
#include <hip/hip_runtime.h>
#include <cstdint>
#include <cstddef>

#define NN 20000
#define NE 320000
#define HD 512
#define NG 400
#define NHID ((size_t)NN * HD)
#define FCK 3072   // padded 3020
#define FCN 256

typedef __attribute__((ext_vector_type(4))) float f32x4;
typedef __attribute__((ext_vector_type(8))) short s16x8;
typedef __attribute__((ext_vector_type(4))) short s16x4;

__device__ __forceinline__ unsigned short f2bf(float f) {
  uint32_t u = __builtin_bit_cast(uint32_t, f);
  uint32_t r = u + 0x7fffu + ((u >> 16) & 1u);
  return (unsigned short)(r >> 16);
}
__device__ __forceinline__ float bf2f(unsigned short h) {
  return __builtin_bit_cast(float, (uint32_t)h << 16);
}

// ---------------- cast x (f32 -> bf16), 4 elems/thread ----------------
__global__ void cast_x_kernel(const float* __restrict__ in, unsigned short* __restrict__ outp) {
  size_t i = ((size_t)blockIdx.x * 256 + threadIdx.x) * 4;
  f32x4 v = *(const f32x4*)(in + i);
  s16x4 o;
  #pragma unroll
  for (int j = 0; j < 4; ++j) o[j] = (short)f2bf(v[j]);
  *(s16x4*)(outp + i) = o;
}

// ---------------- generic LDS-tiled transpose+cast: out[c][r] = bf16(in[r][c]) ----
// in: R x C fp32 (rows r < R valid, else 0). out: C x ldo bf16. grid (ldo/64, C/64, batches)
__global__ __launch_bounds__(256) void transpose_kernel(
    const float* __restrict__ in, unsigned short* __restrict__ outp,
    int R, int C, int ldo, size_t in_bs, size_t out_bs) {
  __shared__ float tl[64][65];
  const float* ip = in + (size_t)blockIdx.z * in_bs;
  unsigned short* op = outp + (size_t)blockIdx.z * out_bs;
  int k0 = blockIdx.x * 64;   // input-row tile
  int j0 = blockIdx.y * 64;   // input-col tile
  int t = threadIdx.x;
  int c = t & 63, r4 = t >> 6;
  #pragma unroll
  for (int rr = 0; rr < 16; ++rr) {
    int r = rr * 4 + r4;
    int k = k0 + r;
    tl[r][c] = (k < R) ? ip[(size_t)k * C + j0 + c] : 0.f;
  }
  __syncthreads();
  #pragma unroll
  for (int jj = 0; jj < 16; ++jj) {
    int j = jj * 4 + r4;
    op[(size_t)(j0 + j) * ldo + k0 + c] = f2bf(tl[c][j]);
  }
}

// ---------------- CSR build: histogram, scan, fill ----------------
__global__ void hist_kernel(const int* __restrict__ ei, int* __restrict__ deg) {
  int e = blockIdx.x * 256 + threadIdx.x;
  if (e >= NE) return;
  atomicAdd(&deg[ei[NE + e]], 1);
}

__global__ __launch_bounds__(1024) void scan_kernel(const int* __restrict__ deg,
                                                    int* __restrict__ rowptr,
                                                    int* __restrict__ cursor) {
  __shared__ int s[1024];
  int t = threadIdx.x;
  int base = t * 20;
  int local[20];
  int sum = 0;
  #pragma unroll
  for (int i = 0; i < 20; ++i) {
    int idx = base + i;
    int d = idx < NN ? deg[idx] : 0;
    local[i] = sum;
    sum += d;
  }
  s[t] = sum;
  __syncthreads();
  for (int off = 1; off < 1024; off <<= 1) {
    int v = (t >= off) ? s[t - off] : 0;
    __syncthreads();
    s[t] += v;
    __syncthreads();
  }
  int pre = (t > 0) ? s[t - 1] : 0;
  #pragma unroll
  for (int i = 0; i < 20; ++i) {
    int idx = base + i;
    if (idx < NN) {
      rowptr[idx] = pre + local[i];
      cursor[idx] = pre + local[i];
    }
  }
  if (t == 1023) rowptr[NN] = s[1023];
}

__global__ void fill_kernel(const int* __restrict__ ei, int* __restrict__ cursor,
                            int* __restrict__ col) {
  int e = blockIdx.x * 256 + threadIdx.x;
  if (e >= NE) return;
  int src = ei[e];
  int dst = ei[NE + e];
  int p = atomicAdd(&cursor[dst], 1);
  col[p] = src;
}

// ---------------- gather-sum: hs[n] = bf16(h[n] + sum_{e: dst=n} h[src]) ----------------
__global__ __launch_bounds__(256) void gather_kernel(
    const unsigned short* __restrict__ hb, const int* __restrict__ rowptr,
    const int* __restrict__ col, unsigned short* __restrict__ hs) {
  int n = blockIdx.x * 4 + (threadIdx.x >> 6);
  int lane = threadIdx.x & 63;
  if (n >= NN) return;
  int lo = rowptr[n], hi = rowptr[n + 1];
  size_t off = (size_t)(lane << 3);
  s16x8 hv = *(const s16x8*)(hb + (size_t)n * HD + off);
  float acc0[8], acc1[8];
  #pragma unroll
  for (int i = 0; i < 8; ++i) {
    acc0[i] = bf2f((unsigned short)hv[i]);
    acc1[i] = 0.f;
  }
  int j = lo;
  for (; j + 2 <= hi; j += 2) {
    int c0 = col[j], c1 = col[j + 1];
    s16x8 v0 = *(const s16x8*)(hb + (size_t)c0 * HD + off);
    s16x8 v1 = *(const s16x8*)(hb + (size_t)c1 * HD + off);
    #pragma unroll
    for (int i = 0; i < 8; ++i) {
      acc0[i] += bf2f((unsigned short)v0[i]);
      acc1[i] += bf2f((unsigned short)v1[i]);
    }
  }
  if (j < hi) {
    s16x8 v0 = *(const s16x8*)(hb + (size_t)col[j] * HD + off);
    #pragma unroll
    for (int i = 0; i < 8; ++i) acc0[i] += bf2f((unsigned short)v0[i]);
  }
  s16x8 o;
  #pragma unroll
  for (int i = 0; i < 8; ++i) o[i] = (short)f2bf(acc0[i] + acc1[i]);
  *(s16x8*)(hs + (size_t)n * HD + off) = o;
}

// ---------------- GEMM (M x 512) @ (512 x 512) with fused epilogue ----------------
// EPI 1: +bias, prelu, BN affine -> bf16 out.  EPI 2: +bias, prelu, relu -> bf16 out
template <int EPI>
__global__ __launch_bounds__(256, 2) void gemm_bf16(
    const unsigned short* __restrict__ A, const unsigned short* __restrict__ Bt,
    const float* __restrict__ bias, const float* __restrict__ slope,
    const float* __restrict__ bnm, const float* __restrict__ bnv,
    const float* __restrict__ bng, const float* __restrict__ bnb,
    unsigned short* __restrict__ Cout, int M) {
  __shared__ unsigned short lds[16384];
  char* ldsb = (char*)lds;
  const int tid = threadIdx.x;
  const int lane = tid & 63;
  const int wid = tid >> 6;
  const int wm = wid >> 1, wn = wid & 1;
  const int m0 = blockIdx.x * 128;
  const int n0 = blockIdx.y * 128;

  f32x4 acc[4][4];
  #pragma unroll
  for (int m = 0; m < 4; ++m)
    #pragma unroll
    for (int n = 0; n < 4; ++n) acc[m][n] = (f32x4){0.f, 0.f, 0.f, 0.f};

  const int row_s = tid >> 3;
  const int slot_s = tid & 7;
  const unsigned ldso_w = (unsigned)(wid << 10);

  for (int kk = 0; kk < HD; kk += 64) {
    __syncthreads();
    #pragma unroll
    for (int i = 0; i < 4; ++i) {
      int ra = i * 32 + row_s;
      int rga = m0 + ra; rga = rga < M ? rga : M - 1;
      const unsigned short* ga = A + (size_t)rga * HD + (kk + ((slot_s ^ (ra & 7)) << 3));
      __builtin_amdgcn_global_load_lds(
          (const __attribute__((address_space(1))) unsigned int*)(const void*)ga,
          (__attribute__((address_space(3))) unsigned int*)(void*)(ldsb + (unsigned)(i * 4096) + ldso_w),
          16, 0, 0);
    }
    #pragma unroll
    for (int i = 0; i < 4; ++i) {
      int rb = i * 32 + row_s;
      const unsigned short* gb = Bt + (size_t)(n0 + rb) * HD + (kk + ((slot_s ^ (rb & 7)) << 3));
      __builtin_amdgcn_global_load_lds(
          (const __attribute__((address_space(1))) unsigned int*)(const void*)gb,
          (__attribute__((address_space(3))) unsigned int*)(void*)(ldsb + 16384u + (unsigned)(i * 4096) + ldso_w),
          16, 0, 0);
    }
    __syncthreads();

    const unsigned swz = (unsigned)((lane & 7) << 4);
    const unsigned koff = (unsigned)((lane >> 4) << 4);
    const unsigned arow = (unsigned)((wm * 64 + (lane & 15)) * 128);
    const unsigned brow = 16384u + (unsigned)((wn * 64 + (lane & 15)) * 128);
    #pragma unroll
    for (int s = 0; s < 2; ++s) {
      s16x8 af[4], bfr[4];
      #pragma unroll
      for (int m = 0; m < 4; ++m)
        af[m] = *(const s16x8*)(ldsb + ((arow + (unsigned)(m * 2048 + s * 64) + koff) ^ swz));
      #pragma unroll
      for (int n = 0; n < 4; ++n)
        bfr[n] = *(const s16x8*)(ldsb + ((brow + (unsigned)(n * 2048 + s * 64) + koff) ^ swz));
      #pragma unroll
      for (int m = 0; m < 4; ++m)
        #pragma unroll
        for (int n = 0; n < 4; ++n)
          acc[m][n] = __builtin_amdgcn_mfma_f32_16x16x32_bf16(af[m], bfr[n], acc[m][n], 0, 0, 0);
    }
  }

  const float al = slope[0];
  const int colb = n0 + wn * 64 + (lane & 15);
  const int rowb = m0 + wm * 64 + ((lane >> 4) << 2);
  #pragma unroll
  for (int n = 0; n < 4; ++n) {
    const int j = colb + n * 16;
    const float bi = bias[j];
    float sc = 1.f, sh = 0.f;
    if (EPI == 1) {
      sc = bng[j] * (1.f / sqrtf(bnv[j] + 1e-5f));
      sh = bnb[j] - bnm[j] * sc;
    }
    #pragma unroll
    for (int m = 0; m < 4; ++m) {
      #pragma unroll
      for (int r = 0; r < 4; ++r) {
        int row = rowb + m * 16 + r;
        if (row < M) {
          float v = acc[m][n][r] + bi;
          v = v >= 0.f ? v : al * v;
          if (EPI == 1) v = v * sc + sh;
          else v = fmaxf(v, 0.f);
          Cout[(size_t)row * HD + j] = f2bf(v);
        }
      }
    }
  }
}

// ---------------- FC1 GEMM: (400 x 3072) @ (3072 x 256), K-split, fp32 partials ----
__global__ __launch_bounds__(256, 2) void fc_gemm_kernel(
    const unsigned short* __restrict__ A, const unsigned short* __restrict__ Bt,
    float* __restrict__ part) {
  __shared__ unsigned short lds[16384];
  char* ldsb = (char*)lds;
  const int tid = threadIdx.x;
  const int lane = tid & 63;
  const int wid = tid >> 6;
  const int wm = wid >> 1, wn = wid & 1;
  const int m0 = blockIdx.x * 128;
  const int n0 = blockIdx.y * 128;
  const int kbase = blockIdx.z * 512;

  f32x4 acc[4][4];
  #pragma unroll
  for (int m = 0; m < 4; ++m)
    #pragma unroll
    for (int n = 0; n < 4; ++n) acc[m][n] = (f32x4){0.f, 0.f, 0.f, 0.f};

  const int row_s = tid >> 3;
  const int slot_s = tid & 7;
  const unsigned ldso_w = (unsigned)(wid << 10);

  for (int kk = kbase; kk < kbase + 512; kk += 64) {
    __syncthreads();
    #pragma unroll
    for (int i = 0; i < 4; ++i) {
      int ra = i * 32 + row_s;
      int rga = m0 + ra; rga = rga < NG ? rga : NG - 1;
      const unsigned short* ga = A + (size_t)rga * FCK + (kk + ((slot_s ^ (ra & 7)) << 3));
      __builtin_amdgcn_global_load_lds(
          (const __attribute__((address_space(1))) unsigned int*)(const void*)ga,
          (__attribute__((address_space(3))) unsigned int*)(void*)(ldsb + (unsigned)(i * 4096) + ldso_w),
          16, 0, 0);
    }
    #pragma unroll
    for (int i = 0; i < 4; ++i) {
      int rb = i * 32 + row_s;
      const unsigned short* gb = Bt + (size_t)(n0 + rb) * FCK + (kk + ((slot_s ^ (rb & 7)) << 3));
      __builtin_amdgcn_global_load_lds(
          (const __attribute__((address_space(1))) unsigned int*)(const void*)gb,
          (__attribute__((address_space(3))) unsigned int*)(void*)(ldsb + 16384u + (unsigned)(i * 4096) + ldso_w),
          16, 0, 0);
    }
    __syncthreads();

    const unsigned swz = (unsigned)((lane & 7) << 4);
    const unsigned koff = (unsigned)((lane >> 4) << 4);
    const unsigned arow = (unsigned)((wm * 64 + (lane & 15)) * 128);
    const unsigned brow = 16384u + (unsigned)((wn * 64 + (lane & 15)) * 128);
    #pragma unroll
    for (int s = 0; s < 2; ++s) {
      s16x8 af[4], bfr[4];
      #pragma unroll
      for (int m = 0; m < 4; ++m)
        af[m] = *(const s16x8*)(ldsb + ((arow + (unsigned)(m * 2048 + s * 64) + koff) ^ swz));
      #pragma unroll
      for (int n = 0; n < 4; ++n)
        bfr[n] = *(const s16x8*)(ldsb + ((brow + (unsigned)(n * 2048 + s * 64) + koff) ^ swz));
      #pragma unroll
      for (int m = 0; m < 4; ++m)
        #pragma unroll
        for (int n = 0; n < 4; ++n)
          acc[m][n] = __builtin_amdgcn_mfma_f32_16x16x32_bf16(af[m], bfr[n], acc[m][n], 0, 0, 0);
    }
  }

  float* po = part + (size_t)blockIdx.z * (NG * FCN);
  const int colb = n0 + wn * 64 + (lane & 15);
  const int rowb = m0 + wm * 64 + ((lane >> 4) << 2);
  #pragma unroll
  for (int n = 0; n < 4; ++n) {
    const int j = colb + n * 16;
    #pragma unroll
    for (int m = 0; m < 4; ++m) {
      #pragma unroll
      for (int r = 0; r < 4; ++r) {
        int row = rowb + m * 16 + r;
        if (row < NG) po[(size_t)row * FCN + j] = acc[m][n][r];
      }
    }
  }
}

// ---------------- pooling (bf16 in): batch sorted -> contiguous segments ----------------
__device__ __forceinline__ int lbound(const int* __restrict__ a, int n, int v) {
  int lo = 0, hi = n;
  while (lo < hi) { int m = (lo + hi) >> 1; if (a[m] < v) lo = m + 1; else hi = m; }
  return lo;
}

__global__ __launch_bounds__(256) void pool_kernel(const unsigned short* __restrict__ hs,
                                                   const int* __restrict__ batch,
                                                   float* __restrict__ pooled) {
  int g = blockIdx.x, t = threadIdx.x;  // 256 threads, 2 cols each
  int lo = lbound(batch, NN, g);
  int hi = lbound(batch, NN, g + 1);
  float s0 = 0.f, s1 = 0.f;
  for (int n = lo; n < hi; ++n) {
    uint32_t v = *(const uint32_t*)(hs + (size_t)n * HD + 2 * t);
    s0 += bf2f((unsigned short)(v & 0xffffu));
    s1 += bf2f((unsigned short)(v >> 16));
  }
  pooled[(size_t)g * HD + 2 * t] = s0;
  pooled[(size_t)g * HD + 2 * t + 1] = s1;
}

// ---------------- x_cat build (bf16, padded to 3072) ----------------
__global__ __launch_bounds__(256) void xcat_kernel(
    const float* __restrict__ pooled, const float* __restrict__ stats,
    const float* __restrict__ adj, unsigned short* __restrict__ xcat) {
  int g = blockIdx.x, t = threadIdx.x;
  unsigned short* row = xcat + (size_t)g * FCK;
  #pragma unroll
  for (int i = t; i < HD; i += 256) row[i] = f2bf(pooled[(size_t)g * HD + i]);
  if (t < 8) row[HD + t] = f2bf(stats[g * 8 + t]);
  for (int i = t; i < 2500; i += 256) row[520 + i] = f2bf(adj[(size_t)g * 2500 + i]);
  if (t < 52) row[3020 + t] = 0;
}

// ---------------- FC epilogue: bias+relu -> x_l, fc2 dot -> sigmoid ----------------
__global__ __launch_bounds__(256) void fc_epi_kernel(
    const float* __restrict__ part, const float* __restrict__ b1,
    const float* __restrict__ w2, const float* __restrict__ b2,
    float* __restrict__ outp) {
  __shared__ float red[256];
  int g = blockIdx.x, t = threadIdx.x;
  float s = b1[t];
  #pragma unroll
  for (int ks = 0; ks < 6; ++ks) s += part[(size_t)ks * (NG * FCN) + g * FCN + t];
  float xl = fmaxf(s, 0.f);
  outp[NG + g * FCN + t] = xl;
  red[t] = xl * w2[t];
  __syncthreads();
  for (int st = 128; st > 0; st >>= 1) {
    if (t < st) red[t] += red[t + st];
    __syncthreads();
  }
  if (t == 0) outp[g] = 1.f / (1.f + expf(-(red[0] + b2[0])));
}

extern "C" void kernel_launch(void* const* d_in, const int* in_sizes, int n_in,
                              void* d_out, int out_size, void* d_ws, size_t ws_size,
                              hipStream_t stream) {
  const float* x = (const float*)d_in[0];
  const int* ei = (const int*)d_in[1];
  const int* batch = (const int*)d_in[2];
  const float* stats = (const float*)d_in[3];
  const float* adj = (const float*)d_in[4];
  const float* w1 = (const float*)d_in[5];
  const float* b1 = (const float*)d_in[6];
  const float* a1 = (const float*)d_in[7];
  const float* bng = (const float*)d_in[8];
  const float* bnb = (const float*)d_in[9];
  const float* bnm = (const float*)d_in[10];
  const float* bnv = (const float*)d_in[11];
  const float* w2 = (const float*)d_in[12];
  const float* b2 = (const float*)d_in[13];
  const float* a2 = (const float*)d_in[14];
  const float* fc1w = (const float*)d_in[15];
  const float* fc1b = (const float*)d_in[16];
  const float* fc2w = (const float*)d_in[17];
  const float* fc2b = (const float*)d_in[18];
  float* outp = (float*)d_out;

  char* ws = (char*)d_ws;
  unsigned short* hb = (unsigned short*)ws;   ws += NHID * 2;        // bf16 h
  unsigned short* hsb = (unsigned short*)ws;  ws += NHID * 2;        // bf16 h+agg / final h
  unsigned short* h1b = (unsigned short*)ws;  ws += NHID * 2;        // bf16 mid
  unsigned short* w1t = (unsigned short*)ws;  ws += (size_t)3 * 512 * 512 * 2;
  unsigned short* w2t = (unsigned short*)ws;  ws += (size_t)3 * 512 * 512 * 2;
  float* pooled = (float*)ws;                 ws += (size_t)NG * HD * 4;
  int* deg = (int*)ws;                        ws += (size_t)NN * 4;
  int* rowptr = (int*)ws;                     ws += (size_t)(NN + 4) * 4;
  int* cursor = (int*)ws;                     ws += (size_t)NN * 4;
  int* col = (int*)ws;                        ws += (size_t)NE * 4;
  unsigned short* xcat = (unsigned short*)ws; ws += (size_t)NG * FCK * 2;
  unsigned short* fc1t = (unsigned short*)ws; ws += (size_t)FCN * FCK * 2;
  float* fcpart = (float*)ws;                 ws += (size_t)6 * NG * FCN * 4;

  // CSR build
  hipMemsetAsync(deg, 0, (size_t)NN * 4, stream);
  hist_kernel<<<(NE + 255) / 256, 256, 0, stream>>>(ei, deg);
  scan_kernel<<<1, 1024, 0, stream>>>(deg, rowptr, cursor);
  fill_kernel<<<(NE + 255) / 256, 256, 0, stream>>>(ei, cursor, col);

  cast_x_kernel<<<(int)(NHID / 1024), 256, 0, stream>>>(x, hb);
  transpose_kernel<<<dim3(8, 8, 3), 256, 0, stream>>>(w1, w1t, 512, 512, 512, 262144, 262144);
  transpose_kernel<<<dim3(8, 8, 3), 256, 0, stream>>>(w2, w2t, 512, 512, 512, 262144, 262144);
  transpose_kernel<<<dim3(FCK / 64, FCN / 64, 1), 256, 0, stream>>>(fc1w, fc1t, 3020, FCN, FCK, 0, 0);

  dim3 ggrid(157, 4, 1);
  for (int l = 0; l < 3; ++l) {
    gather_kernel<<<NN / 4, 256, 0, stream>>>(hb, rowptr, col, hsb);
    gemm_bf16<1><<<ggrid, 256, 0, stream>>>(hsb, w1t + (size_t)l * 262144,
        b1 + l * 512, a1 + l, bnm + l * 512, bnv + l * 512, bng + l * 512, bnb + l * 512,
        h1b, NN);
    gemm_bf16<2><<<ggrid, 256, 0, stream>>>(h1b, w2t + (size_t)l * 262144,
        b2 + l * 512, a2 + l, nullptr, nullptr, nullptr, nullptr,
        (l < 2) ? hb : hsb, NN);
  }

  pool_kernel<<<NG, 256, 0, stream>>>(hsb, batch, pooled);
  xcat_kernel<<<NG, 256, 0, stream>>>(pooled, stats, adj, xcat);
  fc_gemm_kernel<<<dim3(4, 2, 6), 256, 0, stream>>>(xcat, fc1t, fcpart);
  fc_epi_kernel<<<NG, 256, 0, stream>>>(fcpart, fc1b, fc2w, fc2b, outp);
}

// Round 4
// 419.395 us; speedup vs baseline: 31.8331x; 1.0559x over previous
//
#include <hip/hip_runtime.h>
#include <cstdint>
#include <cstddef>

#define NN 20000
#define NE 320000
#define HD 512
#define NG 400
#define NHID ((size_t)NN * HD)
#define FCK 3072   // padded 3020
#define FCN 256

typedef __attribute__((ext_vector_type(4))) float f32x4;
typedef __attribute__((ext_vector_type(8))) short s16x8;
typedef __attribute__((ext_vector_type(4))) short s16x4;

__device__ __forceinline__ unsigned short f2bf(float f) {
  uint32_t u = __builtin_bit_cast(uint32_t, f);
  uint32_t r = u + 0x7fffu + ((u >> 16) & 1u);
  return (unsigned short)(r >> 16);
}
__device__ __forceinline__ float bf2f(unsigned short h) {
  return __builtin_bit_cast(float, (uint32_t)h << 16);
}

// ---------------- cast x (f32 -> bf16), 4 elems/thread ----------------
__global__ void cast_x_kernel(const float* __restrict__ in, unsigned short* __restrict__ outp) {
  size_t i = ((size_t)blockIdx.x * 256 + threadIdx.x) * 4;
  f32x4 v = *(const f32x4*)(in + i);
  s16x4 o;
  #pragma unroll
  for (int j = 0; j < 4; ++j) o[j] = (short)f2bf(v[j]);
  *(s16x4*)(outp + i) = o;
}

// ---------------- generic LDS-tiled transpose+cast: out[c][r] = bf16(in[r][c]) ----
__global__ __launch_bounds__(256) void transpose_kernel(
    const float* __restrict__ in, unsigned short* __restrict__ outp,
    int R, int C, int ldo, size_t in_bs, size_t out_bs) {
  __shared__ float tl[64][65];
  const float* ip = in + (size_t)blockIdx.z * in_bs;
  unsigned short* op = outp + (size_t)blockIdx.z * out_bs;
  int k0 = blockIdx.x * 64;
  int j0 = blockIdx.y * 64;
  int t = threadIdx.x;
  int c = t & 63, r4 = t >> 6;
  #pragma unroll
  for (int rr = 0; rr < 16; ++rr) {
    int r = rr * 4 + r4;
    int k = k0 + r;
    tl[r][c] = (k < R) ? ip[(size_t)k * C + j0 + c] : 0.f;
  }
  __syncthreads();
  #pragma unroll
  for (int jj = 0; jj < 16; ++jj) {
    int j = jj * 4 + r4;
    op[(size_t)(j0 + j) * ldo + k0 + c] = f2bf(tl[c][j]);
  }
}

// ---------------- CSR build: histogram, scan, fill ----------------
__global__ void hist_kernel(const int* __restrict__ ei, int* __restrict__ deg) {
  int e = blockIdx.x * 256 + threadIdx.x;
  if (e >= NE) return;
  atomicAdd(&deg[ei[NE + e]], 1);
}

__global__ __launch_bounds__(1024) void scan_kernel(const int* __restrict__ deg,
                                                    int* __restrict__ rowptr,
                                                    int* __restrict__ cursor) {
  __shared__ int s[1024];
  int t = threadIdx.x;
  int base = t * 20;
  int local[20];
  int sum = 0;
  #pragma unroll
  for (int i = 0; i < 20; ++i) {
    int idx = base + i;
    int d = idx < NN ? deg[idx] : 0;
    local[i] = sum;
    sum += d;
  }
  s[t] = sum;
  __syncthreads();
  for (int off = 1; off < 1024; off <<= 1) {
    int v = (t >= off) ? s[t - off] : 0;
    __syncthreads();
    s[t] += v;
    __syncthreads();
  }
  int pre = (t > 0) ? s[t - 1] : 0;
  #pragma unroll
  for (int i = 0; i < 20; ++i) {
    int idx = base + i;
    if (idx < NN) {
      rowptr[idx] = pre + local[i];
      cursor[idx] = pre + local[i];
    }
  }
  if (t == 1023) rowptr[NN] = s[1023];
}

__global__ void fill_kernel(const int* __restrict__ ei, int* __restrict__ cursor,
                            int* __restrict__ col) {
  int e = blockIdx.x * 256 + threadIdx.x;
  if (e >= NE) return;
  int src = ei[e];
  int dst = ei[NE + e];
  int p = atomicAdd(&cursor[dst], 1);
  col[p] = src;
}

// ---------------- gather-sum: hs[n] = bf16(h[n] + sum_{e: dst=n} h[src]) ----------
// 4 loads in flight per iter, 2 accumulator sets (VGPR <= 64 keeps 8 waves/SIMD)
__global__ __launch_bounds__(256) void gather_kernel(
    const unsigned short* __restrict__ hb, const int* __restrict__ rowptr,
    const int* __restrict__ col, unsigned short* __restrict__ hs) {
  int n = blockIdx.x * 4 + (threadIdx.x >> 6);
  int lane = threadIdx.x & 63;
  if (n >= NN) return;
  int lo = rowptr[n], hi = rowptr[n + 1];
  size_t off = (size_t)(lane << 3);
  const unsigned short* hbl = hb + off;
  s16x8 hv = *(const s16x8*)(hbl + (size_t)n * HD);
  float a0[8], a1[8];
  #pragma unroll
  for (int i = 0; i < 8; ++i) {
    a0[i] = bf2f((unsigned short)hv[i]);
    a1[i] = 0.f;
  }
  int j = lo;
  for (; j + 4 <= hi; j += 4) {
    int c0 = col[j], c1 = col[j + 1], c2 = col[j + 2], c3 = col[j + 3];
    s16x8 v0 = *(const s16x8*)(hbl + (size_t)c0 * HD);
    s16x8 v1 = *(const s16x8*)(hbl + (size_t)c1 * HD);
    s16x8 v2 = *(const s16x8*)(hbl + (size_t)c2 * HD);
    s16x8 v3 = *(const s16x8*)(hbl + (size_t)c3 * HD);
    #pragma unroll
    for (int i = 0; i < 8; ++i) {
      a0[i] += bf2f((unsigned short)v0[i]);
      a1[i] += bf2f((unsigned short)v1[i]);
    }
    #pragma unroll
    for (int i = 0; i < 8; ++i) {
      a0[i] += bf2f((unsigned short)v2[i]);
      a1[i] += bf2f((unsigned short)v3[i]);
    }
  }
  if (j + 2 <= hi) {
    int c0 = col[j], c1 = col[j + 1];
    s16x8 v0 = *(const s16x8*)(hbl + (size_t)c0 * HD);
    s16x8 v1 = *(const s16x8*)(hbl + (size_t)c1 * HD);
    #pragma unroll
    for (int i = 0; i < 8; ++i) {
      a0[i] += bf2f((unsigned short)v0[i]);
      a1[i] += bf2f((unsigned short)v1[i]);
    }
    j += 2;
  }
  if (j < hi) {
    s16x8 v0 = *(const s16x8*)(hbl + (size_t)col[j] * HD);
    #pragma unroll
    for (int i = 0; i < 8; ++i) a0[i] += bf2f((unsigned short)v0[i]);
  }
  s16x8 o;
  #pragma unroll
  for (int i = 0; i < 8; ++i) o[i] = (short)f2bf(a0[i] + a1[i]);
  *(s16x8*)(hs + (size_t)n * HD + off) = o;
}

// ---------------- GEMM (M x 512) @ (512 x 512), XCD-chunked swizzle ----------------
// 1D grid of 628 blocks -> (row 0..156, col 0..3), col-fastest within an XCD chunk
// EPI 1: +bias, prelu, BN affine -> bf16.  EPI 2: +bias, prelu, relu -> bf16
template <int EPI>
__global__ __launch_bounds__(256, 2) void gemm_bf16(
    const unsigned short* __restrict__ A, const unsigned short* __restrict__ Bt,
    const float* __restrict__ bias, const float* __restrict__ slope,
    const float* __restrict__ bnm, const float* __restrict__ bnv,
    const float* __restrict__ bng, const float* __restrict__ bnb,
    unsigned short* __restrict__ Cout, int M) {
  __shared__ unsigned short lds[16384];
  char* ldsb = (char*)lds;
  const int tid = threadIdx.x;
  const int lane = tid & 63;
  const int wid = tid >> 6;
  const int wm = wid >> 1, wn = wid & 1;

  // bijective XCD-chunked swizzle (m204): same-row col-blocks land on one XCD
  const unsigned bid = blockIdx.x;
  const unsigned nwg = gridDim.x;
  const unsigned q = nwg >> 3, r = nwg & 7;
  const unsigned xcd = bid & 7, idx = bid >> 3;
  const unsigned wgid = (xcd < r ? xcd * (q + 1) : r * (q + 1) + (xcd - r) * q) + idx;
  const int m0 = (int)(wgid >> 2) * 128;
  const int n0 = (int)(wgid & 3) * 128;

  f32x4 acc[4][4];
  #pragma unroll
  for (int m = 0; m < 4; ++m)
    #pragma unroll
    for (int n = 0; n < 4; ++n) acc[m][n] = (f32x4){0.f, 0.f, 0.f, 0.f};

  const int row_s = tid >> 3;
  const int slot_s = tid & 7;
  const unsigned ldso_w = (unsigned)(wid << 10);

  for (int kk = 0; kk < HD; kk += 64) {
    __syncthreads();
    #pragma unroll
    for (int i = 0; i < 4; ++i) {
      int ra = i * 32 + row_s;
      int rga = m0 + ra; rga = rga < M ? rga : M - 1;
      const unsigned short* ga = A + (size_t)rga * HD + (kk + ((slot_s ^ (ra & 7)) << 3));
      __builtin_amdgcn_global_load_lds(
          (const __attribute__((address_space(1))) unsigned int*)(const void*)ga,
          (__attribute__((address_space(3))) unsigned int*)(void*)(ldsb + (unsigned)(i * 4096) + ldso_w),
          16, 0, 0);
    }
    #pragma unroll
    for (int i = 0; i < 4; ++i) {
      int rb = i * 32 + row_s;
      const unsigned short* gb = Bt + (size_t)(n0 + rb) * HD + (kk + ((slot_s ^ (rb & 7)) << 3));
      __builtin_amdgcn_global_load_lds(
          (const __attribute__((address_space(1))) unsigned int*)(const void*)gb,
          (__attribute__((address_space(3))) unsigned int*)(void*)(ldsb + 16384u + (unsigned)(i * 4096) + ldso_w),
          16, 0, 0);
    }
    __syncthreads();

    const unsigned swz = (unsigned)((lane & 7) << 4);
    const unsigned koff = (unsigned)((lane >> 4) << 4);
    const unsigned arow = (unsigned)((wm * 64 + (lane & 15)) * 128);
    const unsigned brow = 16384u + (unsigned)((wn * 64 + (lane & 15)) * 128);
    #pragma unroll
    for (int s = 0; s < 2; ++s) {
      s16x8 af[4], bfr[4];
      #pragma unroll
      for (int m = 0; m < 4; ++m)
        af[m] = *(const s16x8*)(ldsb + ((arow + (unsigned)(m * 2048 + s * 64) + koff) ^ swz));
      #pragma unroll
      for (int n = 0; n < 4; ++n)
        bfr[n] = *(const s16x8*)(ldsb + ((brow + (unsigned)(n * 2048 + s * 64) + koff) ^ swz));
      #pragma unroll
      for (int m = 0; m < 4; ++m)
        #pragma unroll
        for (int n = 0; n < 4; ++n)
          acc[m][n] = __builtin_amdgcn_mfma_f32_16x16x32_bf16(af[m], bfr[n], acc[m][n], 0, 0, 0);
    }
  }

  const float al = slope[0];
  const int colb = n0 + wn * 64 + (lane & 15);
  const int rowb = m0 + wm * 64 + ((lane >> 4) << 2);
  #pragma unroll
  for (int n = 0; n < 4; ++n) {
    const int j = colb + n * 16;
    const float bi = bias[j];
    float sc = 1.f, sh = 0.f;
    if (EPI == 1) {
      sc = bng[j] * (1.f / sqrtf(bnv[j] + 1e-5f));
      sh = bnb[j] - bnm[j] * sc;
    }
    #pragma unroll
    for (int m = 0; m < 4; ++m) {
      #pragma unroll
      for (int r2 = 0; r2 < 4; ++r2) {
        int row = rowb + m * 16 + r2;
        if (row < M) {
          float v = acc[m][n][r2] + bi;
          v = v >= 0.f ? v : al * v;
          if (EPI == 1) v = v * sc + sh;
          else v = fmaxf(v, 0.f);
          Cout[(size_t)row * HD + j] = f2bf(v);
        }
      }
    }
  }
}

// ---------------- FC1 GEMM: (400 x 3072) @ (3072 x 256), K-split, fp32 partials ----
__global__ __launch_bounds__(256, 2) void fc_gemm_kernel(
    const unsigned short* __restrict__ A, const unsigned short* __restrict__ Bt,
    float* __restrict__ part) {
  __shared__ unsigned short lds[16384];
  char* ldsb = (char*)lds;
  const int tid = threadIdx.x;
  const int lane = tid & 63;
  const int wid = tid >> 6;
  const int wm = wid >> 1, wn = wid & 1;
  const int m0 = blockIdx.x * 128;
  const int n0 = blockIdx.y * 128;
  const int kbase = blockIdx.z * 512;

  f32x4 acc[4][4];
  #pragma unroll
  for (int m = 0; m < 4; ++m)
    #pragma unroll
    for (int n = 0; n < 4; ++n) acc[m][n] = (f32x4){0.f, 0.f, 0.f, 0.f};

  const int row_s = tid >> 3;
  const int slot_s = tid & 7;
  const unsigned ldso_w = (unsigned)(wid << 10);

  for (int kk = kbase; kk < kbase + 512; kk += 64) {
    __syncthreads();
    #pragma unroll
    for (int i = 0; i < 4; ++i) {
      int ra = i * 32 + row_s;
      int rga = m0 + ra; rga = rga < NG ? rga : NG - 1;
      const unsigned short* ga = A + (size_t)rga * FCK + (kk + ((slot_s ^ (ra & 7)) << 3));
      __builtin_amdgcn_global_load_lds(
          (const __attribute__((address_space(1))) unsigned int*)(const void*)ga,
          (__attribute__((address_space(3))) unsigned int*)(void*)(ldsb + (unsigned)(i * 4096) + ldso_w),
          16, 0, 0);
    }
    #pragma unroll
    for (int i = 0; i < 4; ++i) {
      int rb = i * 32 + row_s;
      const unsigned short* gb = Bt + (size_t)(n0 + rb) * FCK + (kk + ((slot_s ^ (rb & 7)) << 3));
      __builtin_amdgcn_global_load_lds(
          (const __attribute__((address_space(1))) unsigned int*)(const void*)gb,
          (__attribute__((address_space(3))) unsigned int*)(void*)(ldsb + 16384u + (unsigned)(i * 4096) + ldso_w),
          16, 0, 0);
    }
    __syncthreads();

    const unsigned swz = (unsigned)((lane & 7) << 4);
    const unsigned koff = (unsigned)((lane >> 4) << 4);
    const unsigned arow = (unsigned)((wm * 64 + (lane & 15)) * 128);
    const unsigned brow = 16384u + (unsigned)((wn * 64 + (lane & 15)) * 128);
    #pragma unroll
    for (int s = 0; s < 2; ++s) {
      s16x8 af[4], bfr[4];
      #pragma unroll
      for (int m = 0; m < 4; ++m)
        af[m] = *(const s16x8*)(ldsb + ((arow + (unsigned)(m * 2048 + s * 64) + koff) ^ swz));
      #pragma unroll
      for (int n = 0; n < 4; ++n)
        bfr[n] = *(const s16x8*)(ldsb + ((brow + (unsigned)(n * 2048 + s * 64) + koff) ^ swz));
      #pragma unroll
      for (int m = 0; m < 4; ++m)
        #pragma unroll
        for (int n = 0; n < 4; ++n)
          acc[m][n] = __builtin_amdgcn_mfma_f32_16x16x32_bf16(af[m], bfr[n], acc[m][n], 0, 0, 0);
    }
  }

  float* po = part + (size_t)blockIdx.z * (NG * FCN);
  const int colb = n0 + wn * 64 + (lane & 15);
  const int rowb = m0 + wm * 64 + ((lane >> 4) << 2);
  #pragma unroll
  for (int n = 0; n < 4; ++n) {
    const int j = colb + n * 16;
    #pragma unroll
    for (int m = 0; m < 4; ++m) {
      #pragma unroll
      for (int r = 0; r < 4; ++r) {
        int row = rowb + m * 16 + r;
        if (row < NG) po[(size_t)row * FCN + j] = acc[m][n][r];
      }
    }
  }
}

// ---------------- pooling (bf16 in): batch sorted -> contiguous segments ----------------
__device__ __forceinline__ int lbound(const int* __restrict__ a, int n, int v) {
  int lo = 0, hi = n;
  while (lo < hi) { int m = (lo + hi) >> 1; if (a[m] < v) lo = m + 1; else hi = m; }
  return lo;
}

__global__ __launch_bounds__(256) void pool_kernel(const unsigned short* __restrict__ hs,
                                                   const int* __restrict__ batch,
                                                   float* __restrict__ pooled) {
  int g = blockIdx.x, t = threadIdx.x;
  int lo = lbound(batch, NN, g);
  int hi = lbound(batch, NN, g + 1);
  float s0 = 0.f, s1 = 0.f;
  for (int n = lo; n < hi; ++n) {
    uint32_t v = *(const uint32_t*)(hs + (size_t)n * HD + 2 * t);
    s0 += bf2f((unsigned short)(v & 0xffffu));
    s1 += bf2f((unsigned short)(v >> 16));
  }
  pooled[(size_t)g * HD + 2 * t] = s0;
  pooled[(size_t)g * HD + 2 * t + 1] = s1;
}

// ---------------- x_cat build (bf16, padded to 3072) ----------------
__global__ __launch_bounds__(256) void xcat_kernel(
    const float* __restrict__ pooled, const float* __restrict__ stats,
    const float* __restrict__ adj, unsigned short* __restrict__ xcat) {
  int g = blockIdx.x, t = threadIdx.x;
  unsigned short* row = xcat + (size_t)g * FCK;
  #pragma unroll
  for (int i = t; i < HD; i += 256) row[i] = f2bf(pooled[(size_t)g * HD + i]);
  if (t < 8) row[HD + t] = f2bf(stats[g * 8 + t]);
  for (int i = t; i < 2500; i += 256) row[520 + i] = f2bf(adj[(size_t)g * 2500 + i]);
  if (t < 52) row[3020 + t] = 0;
}

// ---------------- FC epilogue: bias+relu -> x_l, fc2 dot -> sigmoid ----------------
__global__ __launch_bounds__(256) void fc_epi_kernel(
    const float* __restrict__ part, const float* __restrict__ b1,
    const float* __restrict__ w2, const float* __restrict__ b2,
    float* __restrict__ outp) {
  __shared__ float red[256];
  int g = blockIdx.x, t = threadIdx.x;
  float s = b1[t];
  #pragma unroll
  for (int ks = 0; ks < 6; ++ks) s += part[(size_t)ks * (NG * FCN) + g * FCN + t];
  float xl = fmaxf(s, 0.f);
  outp[NG + g * FCN + t] = xl;
  red[t] = xl * w2[t];
  __syncthreads();
  for (int st = 128; st > 0; st >>= 1) {
    if (t < st) red[t] += red[t + st];
    __syncthreads();
  }
  if (t == 0) outp[g] = 1.f / (1.f + expf(-(red[0] + b2[0])));
}

extern "C" void kernel_launch(void* const* d_in, const int* in_sizes, int n_in,
                              void* d_out, int out_size, void* d_ws, size_t ws_size,
                              hipStream_t stream) {
  const float* x = (const float*)d_in[0];
  const int* ei = (const int*)d_in[1];
  const int* batch = (const int*)d_in[2];
  const float* stats = (const float*)d_in[3];
  const float* adj = (const float*)d_in[4];
  const float* w1 = (const float*)d_in[5];
  const float* b1 = (const float*)d_in[6];
  const float* a1 = (const float*)d_in[7];
  const float* bng = (const float*)d_in[8];
  const float* bnb = (const float*)d_in[9];
  const float* bnm = (const float*)d_in[10];
  const float* bnv = (const float*)d_in[11];
  const float* w2 = (const float*)d_in[12];
  const float* b2 = (const float*)d_in[13];
  const float* a2 = (const float*)d_in[14];
  const float* fc1w = (const float*)d_in[15];
  const float* fc1b = (const float*)d_in[16];
  const float* fc2w = (const float*)d_in[17];
  const float* fc2b = (const float*)d_in[18];
  float* outp = (float*)d_out;

  char* ws = (char*)d_ws;
  unsigned short* hb = (unsigned short*)ws;   ws += NHID * 2;
  unsigned short* hsb = (unsigned short*)ws;  ws += NHID * 2;
  unsigned short* h1b = (unsigned short*)ws;  ws += NHID * 2;
  unsigned short* w1t = (unsigned short*)ws;  ws += (size_t)3 * 512 * 512 * 2;
  unsigned short* w2t = (unsigned short*)ws;  ws += (size_t)3 * 512 * 512 * 2;
  float* pooled = (float*)ws;                 ws += (size_t)NG * HD * 4;
  int* deg = (int*)ws;                        ws += (size_t)NN * 4;
  int* rowptr = (int*)ws;                     ws += (size_t)(NN + 4) * 4;
  int* cursor = (int*)ws;                     ws += (size_t)NN * 4;
  int* col = (int*)ws;                        ws += (size_t)NE * 4;
  unsigned short* xcat = (unsigned short*)ws; ws += (size_t)NG * FCK * 2;
  unsigned short* fc1t = (unsigned short*)ws; ws += (size_t)FCN * FCK * 2;
  float* fcpart = (float*)ws;                 ws += (size_t)6 * NG * FCN * 4;

  // CSR build
  hipMemsetAsync(deg, 0, (size_t)NN * 4, stream);
  hist_kernel<<<(NE + 255) / 256, 256, 0, stream>>>(ei, deg);
  scan_kernel<<<1, 1024, 0, stream>>>(deg, rowptr, cursor);
  fill_kernel<<<(NE + 255) / 256, 256, 0, stream>>>(ei, cursor, col);

  cast_x_kernel<<<(int)(NHID / 1024), 256, 0, stream>>>(x, hb);
  transpose_kernel<<<dim3(8, 8, 3), 256, 0, stream>>>(w1, w1t, 512, 512, 512, 262144, 262144);
  transpose_kernel<<<dim3(8, 8, 3), 256, 0, stream>>>(w2, w2t, 512, 512, 512, 262144, 262144);
  transpose_kernel<<<dim3(FCK / 64, FCN / 64, 1), 256, 0, stream>>>(fc1w, fc1t, 3020, FCN, FCK, 0, 0);

  for (int l = 0; l < 3; ++l) {
    gather_kernel<<<NN / 4, 256, 0, stream>>>(hb, rowptr, col, hsb);
    gemm_bf16<1><<<628, 256, 0, stream>>>(hsb, w1t + (size_t)l * 262144,
        b1 + l * 512, a1 + l, bnm + l * 512, bnv + l * 512, bng + l * 512, bnb + l * 512,
        h1b, NN);
    gemm_bf16<2><<<628, 256, 0, stream>>>(h1b, w2t + (size_t)l * 262144,
        b2 + l * 512, a2 + l, nullptr, nullptr, nullptr, nullptr,
        (l < 2) ? hb : hsb, NN);
  }

  pool_kernel<<<NG, 256, 0, stream>>>(hsb, batch, pooled);
  xcat_kernel<<<NG, 256, 0, stream>>>(pooled, stats, adj, xcat);
  fc_gemm_kernel<<<dim3(4, 2, 6), 256, 0, stream>>>(xcat, fc1t, fcpart);
  fc_epi_kernel<<<NG, 256, 0, stream>>>(fcpart, fc1b, fc2w, fc2b, outp);
}